// Round 10
// baseline (993.279 us; speedup 1.0000x reference)
//
#include <hip/hip_runtime.h>

#define NPTS   32768
#define DIM    256
#define KCODES 8192
#define TAU    2e-4f

typedef __attribute__((ext_vector_type(8))) short bf16x8;
typedef __attribute__((ext_vector_type(4))) float f32x4;

__device__ __forceinline__ unsigned short f2bf(float x) {  // RNE bf16
  unsigned u = __float_as_uint(x);
  unsigned r = (u + 0x7fffu + ((u >> 16) & 1u)) >> 16;
  return (unsigned short)r;
}
__device__ __forceinline__ float bf2f(unsigned short b) {
  return __uint_as_float(((unsigned)b) << 16);
}

// ---------------- fused hi/lo split + row squared-norms ----------------
__global__ __launch_bounds__(256) void split_norms_kernel(
    const float* __restrict__ src, unsigned short* __restrict__ hi,
    unsigned short* __restrict__ lo, float* __restrict__ norms,
    int* __restrict__ flagcnt) {
  if (flagcnt && blockIdx.x == 0 && threadIdx.x == 0) *flagcnt = 0;
  int row = blockIdx.x * 4 + (threadIdx.x >> 6);
  int lane = threadIdx.x & 63;
  float4 a = reinterpret_cast<const float4*>(src)[row * 64 + lane];
  ushort4 hq, lq;
  hq.x = f2bf(a.x); lq.x = f2bf(a.x - bf2f(hq.x));
  hq.y = f2bf(a.y); lq.y = f2bf(a.y - bf2f(hq.y));
  hq.z = f2bf(a.z); lq.z = f2bf(a.z - bf2f(hq.z));
  hq.w = f2bf(a.w); lq.w = f2bf(a.w - bf2f(hq.w));
  reinterpret_cast<ushort4*>(hi)[row * 64 + lane] = hq;
  reinterpret_cast<ushort4*>(lo)[row * 64 + lane] = lq;
  float sx = a.x * a.x, sy = a.y * a.y, sz = a.z * a.z, sw = a.w * a.w;
  double s = (double)sx + (double)sy + (double)sz + (double)sw;
#pragma unroll
  for (int m = 32; m; m >>= 1) s += __shfl_xor(s, m, 64);
  if (lane == 0) norms[row] = (float)s;
}

// standalone norms (fallback path)
__global__ __launch_bounds__(256) void norms_kernel(const float* __restrict__ src,
                                                    float* __restrict__ dst) {
  int row = blockIdx.x * 4 + (threadIdx.x >> 6);
  int lane = threadIdx.x & 63;
  float4 a = reinterpret_cast<const float4*>(src)[row * 64 + lane];
  float sx = a.x * a.x, sy = a.y * a.y, sz = a.z * a.z, sw = a.w * a.w;
  double s = (double)sx + (double)sy + (double)sz + (double)sw;
#pragma unroll
  for (int m = 32; m; m >>= 1) s += __shfl_xor(s, m, 64);
  if (lane == 0) dst[row] = (float)s;
}

// ---------------- MFMA distance GEMM + per-point top-2 (64x64 wave tile) -----
// 8 waves (2 wrow x 4 wcol), block 128 pts x 256 codes/cc, wave 64x64
// (4x4 subtiles, acc 16 f32x4 -> AGPRs). r8's 2-barrier single-buffer stage
// (proven 2 blocks/CU overlap). Running top-2 per (pt, wcol) lives in LDS
// (6KB), updated per cc-tile -- keeps arch VGPRs ~80 (cap is 128).
__global__ __launch_bounds__(512, 2) void mfma_argmin_kernel(
    const unsigned short* __restrict__ hh, const unsigned short* __restrict__ hl,
    const unsigned short* __restrict__ ch, const unsigned short* __restrict__ cl,
    const float* __restrict__ h2f, const float* __restrict__ c2f,
    float* __restrict__ bv, int* __restrict__ bi, float* __restrict__ b2o) {
  __shared__ __align__(16) unsigned short As0[4096], As1[4096];   // 8+8 KB
  __shared__ __align__(16) unsigned short Bs0[8192], Bs1[8192];   // 16+16 KB
  __shared__ float tb1[128][4], tb2[128][4];                      // 4 KB
  __shared__ int ti1[128][4];                                     // 2 KB
  const int t = threadIdx.x;
  const int lane = t & 63;
  const int wid = t >> 6;
  const int wrow = wid >> 2, wcol = wid & 3;
  const int b = blockIdx.x;
  const int v = (b & 7) * 64 + (b >> 3);   // XCD-chunked bijective swizzle
  const int sblk = v >> 8, pblk = v & 255;
  const int p0 = pblk * 128;
  const int cbase = sblk * (KCODES / 2);

  // staging: 512 threads; A (128 rows x 4 chunks): 1 uint4 per array; B: 2.
  const int strow = t >> 2, stchunk = t & 3;
  const int stswz = ((stchunk ^ ((strow >> 1) & 3)) << 4);
  const int a_lds = strow * 64 + stswz;
  const int b_lds0 = strow * 64 + stswz;
  const int b_lds1 = b_lds0 + 128 * 64;
  const uint4* hh4 = (const uint4*)hh;
  const uint4* hl4 = (const uint4*)hl;
  const uint4* ch4 = (const uint4*)ch;
  const uint4* cl4 = (const uint4*)cl;
  const int a_g = (p0 + strow) * 32 + stchunk;             // + dd*4
  const int b_gbase = (cbase + strow) * 32 + stchunk;      // + cc*8192 + dd*4 (+128*32)

  // fragment read offsets
  const int flane = lane & 15, fch = lane >> 4;
  int aoff[4], boff[4];
#pragma unroll
  for (int sr = 0; sr < 4; ++sr) {
    int ar = wrow * 64 + sr * 16 + flane;
    aoff[sr] = ar * 64 + ((fch ^ ((ar >> 1) & 3)) << 4);
  }
#pragma unroll
  for (int sc = 0; sc < 4; ++sc) {
    int br = wcol * 64 + sc * 16 + flane;
    boff[sc] = br * 64 + ((fch ^ ((br >> 1) & 3)) << 4);
  }

  float h2r[16];
#pragma unroll
  for (int sr = 0; sr < 4; ++sr)
#pragma unroll
    for (int r = 0; r < 4; ++r)
      h2r[sr * 4 + r] = h2f[p0 + wrow * 64 + sr * 16 + fch * 4 + r];

  // init LDS top-2 state: 512 entries, one per thread
  tb1[t >> 2][t & 3] = 3.4e38f;
  tb2[t >> 2][t & 3] = 3.4e38f;
  ti1[t >> 2][t & 3] = 0;

#pragma unroll 1
  for (int cc = 0; cc < 16; ++cc) {
    f32x4 acc[16];
#pragma unroll
    for (int q = 0; q < 16; ++q) acc[q] = (f32x4){0.f, 0.f, 0.f, 0.f};
    const int b_g = b_gbase + cc * 256 * 32;

#pragma unroll 1
    for (int dd = 0; dd < 8; ++dd) {
      uint4 va0 = hh4[a_g + dd * 4];
      uint4 va1 = hl4[a_g + dd * 4];
      uint4 vb00 = ch4[b_g + dd * 4];
      uint4 vb01 = ch4[b_g + 128 * 32 + dd * 4];
      uint4 vb10 = cl4[b_g + dd * 4];
      uint4 vb11 = cl4[b_g + 128 * 32 + dd * 4];
      __syncthreads();
      *(uint4*)((char*)As0 + a_lds) = va0;
      *(uint4*)((char*)As1 + a_lds) = va1;
      *(uint4*)((char*)Bs0 + b_lds0) = vb00;
      *(uint4*)((char*)Bs0 + b_lds1) = vb01;
      *(uint4*)((char*)Bs1 + b_lds0) = vb10;
      *(uint4*)((char*)Bs1 + b_lds1) = vb11;
      __syncthreads();
      bf16x8 ah[4], al[4];
#pragma unroll
      for (int sr = 0; sr < 4; ++sr) {
        ah[sr] = *(const bf16x8*)((const char*)As0 + aoff[sr]);
        al[sr] = *(const bf16x8*)((const char*)As1 + aoff[sr]);
      }
#pragma unroll
      for (int sc = 0; sc < 4; ++sc) {
        bf16x8 bh = *(const bf16x8*)((const char*)Bs0 + boff[sc]);
        bf16x8 bl = *(const bf16x8*)((const char*)Bs1 + boff[sc]);
#pragma unroll
        for (int sr = 0; sr < 4; ++sr) {
          acc[sc * 4 + sr] = __builtin_amdgcn_mfma_f32_16x16x32_bf16(ah[sr], bh, acc[sc * 4 + sr], 0, 0, 0);
          acc[sc * 4 + sr] = __builtin_amdgcn_mfma_f32_16x16x32_bf16(al[sr], bh, acc[sc * 4 + sr], 0, 0, 0);
          acc[sc * 4 + sr] = __builtin_amdgcn_mfma_f32_16x16x32_bf16(ah[sr], bl, acc[sc * 4 + sr], 0, 0, 0);
        }
      }
    }
    // epilogue: numpy-fp32 scores, per-slot top-2, lane-merge, LDS RMW
    int cols[4];
    float c2v[4];
#pragma unroll
    for (int sc = 0; sc < 4; ++sc) {
      cols[sc] = cbase + cc * 256 + wcol * 64 + sc * 16 + flane;
      c2v[sc] = c2f[cols[sc]];
    }
#pragma unroll
    for (int slot = 0; slot < 16; ++slot) {
      const int sr = slot >> 2, r = slot & 3;
      float b1 = 3.4e38f, b2 = 3.4e38f;
      int i1 = 0;
#pragma unroll
      for (int sc = 0; sc < 4; ++sc) {
        float A2 = h2r[slot] + c2v[sc];                 // fl32(h2+c2)
        float s = fmaf(-2.f, acc[sc * 4 + sr][r], A2);  // fl32(A - 2*dot)
        if (s < b1) { b2 = b1; b1 = s; i1 = cols[sc]; }
        else if (s < b2) b2 = s;
      }
#pragma unroll
      for (int m = 1; m <= 8; m <<= 1) {
        float ob1 = __shfl_xor(b1, m, 64);
        int oi1 = __shfl_xor(i1, m, 64);
        float ob2 = __shfl_xor(b2, m, 64);
        float loser = fmaxf(b1, ob1);
        float nb2 = fminf(fminf(b2, ob2), loser);
        if (ob1 < b1 || (ob1 == b1 && oi1 < i1)) { b1 = ob1; i1 = oi1; }
        b2 = nb2;
      }
      if (flane == 0) {
        int pl = wrow * 64 + sr * 16 + fch * 4 + r;
        float gb1 = tb1[pl][wcol], gb2 = tb2[pl][wcol];
        int gi1 = ti1[pl][wcol];
        float loser = fmaxf(gb1, b1);
        float nb2 = fminf(fminf(gb2, b2), loser);
        if (b1 < gb1 || (b1 == gb1 && i1 < gi1)) { gb1 = b1; gi1 = i1; }
        tb1[pl][wcol] = gb1;
        ti1[pl][wcol] = gi1;
        tb2[pl][wcol] = nb2;
      }
    }
  }
  __syncthreads();
  // writeout: merge 4 wcol entries per point, idx tiebreak
  if (t < 128) {
    float b1 = tb1[t][0], b2 = tb2[t][0];
    int i1 = ti1[t][0];
#pragma unroll
    for (int w = 1; w < 4; ++w) {
      float nb1 = tb1[t][w], nb2v = tb2[t][w];
      int ni1 = ti1[t][w];
      float loser = fmaxf(b1, nb1);
      float m2 = fminf(fminf(b2, nb2v), loser);
      if (nb1 < b1 || (nb1 == b1 && ni1 < i1)) { b1 = nb1; i1 = ni1; }
      b2 = m2;
    }
    int p = p0 + t;
    bv[sblk * NPTS + p] = b1;
    bi[sblk * NPTS + p] = i1;
    b2o[sblk * NPTS + p] = b2;
  }
}

// ---------------- merge 2 slices + flag near-ties ----------------
__global__ __launch_bounds__(256) void merge_flag_kernel(
    const float* __restrict__ bv, const int* __restrict__ bi,
    const float* __restrict__ b2o, int* __restrict__ idx,
    float* __restrict__ out_idx_f, int* __restrict__ flagcnt,
    int* __restrict__ flaglist) {
  int p = blockIdx.x * 256 + threadIdx.x;
  float b1 = bv[p]; int i1 = bi[p]; float b2 = b2o[p];
  {
    float pb1 = bv[NPTS + p];
    int pi1 = bi[NPTS + p];
    float pb2 = b2o[NPTS + p];
    float loser = fmaxf(b1, pb1);
    float nb2 = fminf(fminf(b2, pb2), loser);
    if (pb1 < b1 || (pb1 == b1 && pi1 < i1)) { b1 = pb1; i1 = pi1; }
    b2 = nb2;
  }
  idx[p] = i1;
  out_idx_f[p] = (float)i1;
  if (b2 - b1 < TAU) { int s = atomicAdd(flagcnt, 1); flaglist[s] = p; }
}

// ---------------- exact numpy-semantics re-argmin for flagged points ----------
__global__ __launch_bounds__(256) void refine_kernel(
    const float* __restrict__ h, const float* __restrict__ cb,
    const float* __restrict__ h2f, const float* __restrict__ c2f,
    const int* __restrict__ flagcnt, const int* __restrict__ flaglist,
    int* __restrict__ idx, float* __restrict__ out_idx_f) {
  __shared__ float hrow[DIM];
  __shared__ float rb[256];
  __shared__ int ri[256];
  const int n = *flagcnt;
  for (int e = blockIdx.x; e < n; e += gridDim.x) {
    const int p = flaglist[e];
    __syncthreads();
    if (threadIdx.x < DIM / 4)
      reinterpret_cast<float4*>(hrow)[threadIdx.x] =
          reinterpret_cast<const float4*>(h + p * DIM)[threadIdx.x];
    __syncthreads();
    const float h2 = h2f[p];
    float b1 = 3.4e38f;
    int i1 = 0x7fffffff;
    for (int c = threadIdx.x; c < KCODES; c += 256) {
      const float4* crow = reinterpret_cast<const float4*>(cb + c * DIM);
      float dot = 0.f;
#pragma unroll 16
      for (int d4 = 0; d4 < DIM / 4; ++d4) {
        float4 cv = crow[d4];
        dot = fmaf(hrow[4 * d4 + 0], cv.x, dot);
        dot = fmaf(hrow[4 * d4 + 1], cv.y, dot);
        dot = fmaf(hrow[4 * d4 + 2], cv.z, dot);
        dot = fmaf(hrow[4 * d4 + 3], cv.w, dot);
      }
      float A = h2 + c2f[c];
      float s = fmaf(-2.f, dot, A);
      if (s < b1) { b1 = s; i1 = c; }
    }
    rb[threadIdx.x] = b1;
    ri[threadIdx.x] = i1;
    __syncthreads();
    for (int step = 128; step; step >>= 1) {
      if (threadIdx.x < step) {
        float ob = rb[threadIdx.x + step];
        int oi = ri[threadIdx.x + step];
        if (ob < rb[threadIdx.x] || (ob == rb[threadIdx.x] && oi < ri[threadIdx.x])) {
          rb[threadIdx.x] = ob;
          ri[threadIdx.x] = oi;
        }
      }
      __syncthreads();
    }
    if (threadIdx.x == 0) { idx[p] = ri[0]; out_idx_f[p] = (float)ri[0]; }
  }
}

// ---------------- fallback: r7 fp32 argmin (8x8 tile) + 2-way merge ----------
__global__ __launch_bounds__(512, 2) void argmin_fp32_kernel(
    const float* __restrict__ h, const float* __restrict__ cb,
    const float* __restrict__ h2f, const float* __restrict__ c2f,
    float* __restrict__ bestval, int* __restrict__ bestidx) {
  __shared__ float hs[16][132];
  __shared__ float cs[16][260];
  const int t = threadIdx.x;
  const int ct = t & 31;
  const int pt = t >> 5;
  const int b = blockIdx.x;
  const int v = (b & 7) * 64 + (b >> 3);
  const int sblk = v >> 8;
  const int pblk = v & 255;
  const int p0 = pblk * 128;
  const int cbase = sblk * (KCODES / 2);
  float best[8]; int besti[8]; float h2r[8];
#pragma unroll
  for (int i = 0; i < 8; ++i) {
    best[i] = 3.4e38f; besti[i] = 0;
    h2r[i] = h2f[p0 + pt * 4 + ((i >> 2) << 6) + (i & 3)];
  }
#pragma unroll 1
  for (int cc = 0; cc < (KCODES / 2) / 256; ++cc) {
    const int c0 = cbase + cc * 256;
    float dot[8][8];
#pragma unroll
    for (int i = 0; i < 8; ++i)
#pragma unroll
      for (int j = 0; j < 8; ++j) dot[i][j] = 0.f;
#pragma unroll 1
    for (int dd = 0; dd < DIM / 16; ++dd) {
      const int d0 = dd * 16;
      {
        int p = t >> 2, k4 = (t & 3) << 2;
        float4 w = *reinterpret_cast<const float4*>(h + (p0 + p) * DIM + d0 + k4);
        hs[k4 + 0][p] = w.x; hs[k4 + 1][p] = w.y;
        hs[k4 + 2][p] = w.z; hs[k4 + 3][p] = w.w;
      }
#pragma unroll
      for (int l = 0; l < 2; ++l) {
        int F = t + l * 512;
        int c = F >> 2, k4 = (F & 3) << 2;
        float4 w = *reinterpret_cast<const float4*>(cb + (c0 + c) * DIM + d0 + k4);
        cs[k4 + 0][c] = w.x; cs[k4 + 1][c] = w.y;
        cs[k4 + 2][c] = w.z; cs[k4 + 3][c] = w.w;
      }
      __syncthreads();
#pragma unroll
      for (int k = 0; k < 16; ++k) {
        float hv[8], cv[8];
        *reinterpret_cast<float4*>(&hv[0]) = *reinterpret_cast<const float4*>(&hs[k][pt * 4]);
        *reinterpret_cast<float4*>(&hv[4]) = *reinterpret_cast<const float4*>(&hs[k][pt * 4 + 64]);
        *reinterpret_cast<float4*>(&cv[0]) = *reinterpret_cast<const float4*>(&cs[k][ct * 4]);
        *reinterpret_cast<float4*>(&cv[4]) = *reinterpret_cast<const float4*>(&cs[k][ct * 4 + 128]);
#pragma unroll
        for (int i = 0; i < 8; ++i)
#pragma unroll
          for (int j = 0; j < 8; ++j) dot[i][j] = fmaf(hv[i], cv[j], dot[i][j]);
      }
      __syncthreads();
    }
#pragma unroll
    for (int j = 0; j < 8; ++j) {
      int cl = c0 + (ct << 2) + ((j >> 2) << 7) + (j & 3);
      float cc2 = c2f[cl];
#pragma unroll
      for (int i = 0; i < 8; ++i) {
        float A = h2r[i] + cc2;
        float s = A - 2.0f * dot[i][j];
        if (s < best[i]) { best[i] = s; besti[i] = cl; }
      }
    }
  }
#pragma unroll
  for (int i = 0; i < 8; ++i) {
    float b1 = best[i]; int i1 = besti[i];
#pragma unroll
    for (int m = 16; m; m >>= 1) {
      float so = __shfl_xor(b1, m, 64);
      int io = __shfl_xor(i1, m, 64);
      if (so < b1 || (so == b1 && io < i1)) { b1 = so; i1 = io; }
    }
    if (ct == 0) {
      int p = p0 + pt * 4 + ((i >> 2) << 6) + (i & 3);
      bestval[sblk * NPTS + p] = b1;
      bestidx[sblk * NPTS + p] = i1;
    }
  }
}

__global__ __launch_bounds__(256) void merge2_kernel(
    const float* __restrict__ bestval, const int* __restrict__ bestidx,
    int* __restrict__ idx, float* __restrict__ out_idx_f) {
  int p = blockIdx.x * 256 + threadIdx.x;
  float v0 = bestval[p], v1 = bestval[NPTS + p];
  int i0 = bestidx[p], i1 = bestidx[NPTS + p];
  int w = (v1 < v0) ? i1 : i0;
  idx[p] = w;
  out_idx_f[p] = (float)w;
}

// ---------------- gather + finalize ----------------
__global__ __launch_bounds__(256) void gather_kernel(
    const float* __restrict__ h, const float* __restrict__ cb,
    const unsigned char* __restrict__ maskb, const int* __restrict__ idx,
    float* __restrict__ zq, float* __restrict__ partial) {
  int p = blockIdx.x * 4 + (threadIdx.x >> 6);
  int lane = threadIdx.x & 63;
  int ci = idx[p];
  float4 hv = reinterpret_cast<const float4*>(h)[p * (DIM / 4) + lane];
  float4 zv = reinterpret_cast<const float4*>(cb)[ci * (DIM / 4) + lane];
  float4 q;
  q.x = hv.x + (zv.x - hv.x);
  q.y = hv.y + (zv.y - hv.y);
  q.z = hv.z + (zv.z - hv.z);
  q.w = hv.w + (zv.w - hv.w);
  reinterpret_cast<float4*>(zq)[p * (DIM / 4) + lane] = q;
  float dx = hv.x - zv.x, dy = hv.y - zv.y, dz = hv.z - zv.z, dw = hv.w - zv.w;
  float s = (maskb[p] != 0) ? (dx * dx + dy * dy + dz * dz + dw * dw) : 0.f;
#pragma unroll
  for (int m = 32; m; m >>= 1) s += __shfl_xor(s, m, 64);
  __shared__ float bs[4];
  if (lane == 0) bs[threadIdx.x >> 6] = s;
  __syncthreads();
  if (threadIdx.x == 0) partial[blockIdx.x] = bs[0] + bs[1] + bs[2] + bs[3];
}

__global__ __launch_bounds__(256) void finalize_kernel(
    const float* __restrict__ partial, const unsigned char* __restrict__ maskb,
    float* __restrict__ out_losses) {
  __shared__ float red[256];
  __shared__ int redi[256];
  float s = 0.f;
  for (int i = threadIdx.x; i < NPTS / 4; i += 256) s += partial[i];
  int cnt = 0;
  for (int i = threadIdx.x; i < NPTS; i += 256) cnt += (maskb[i] != 0);
  red[threadIdx.x] = s;
  redi[threadIdx.x] = cnt;
  __syncthreads();
  for (int step = 128; step; step >>= 1) {
    if (threadIdx.x < step) {
      red[threadIdx.x] += red[threadIdx.x + step];
      redi[threadIdx.x] += redi[threadIdx.x + step];
    }
    __syncthreads();
  }
  if (threadIdx.x == 0) {
    float denom = (float)redi[0] * (float)DIM + 1e-8f;
    float loss = red[0] / denom;
    out_losses[0] = loss;
    out_losses[1] = loss;
  }
}

extern "C" void kernel_launch(void* const* d_in, const int* in_sizes, int n_in,
                              void* d_out, int out_size, void* d_ws, size_t ws_size,
                              hipStream_t stream) {
  const float* h = (const float*)d_in[0];
  const unsigned char* maskb = (const unsigned char*)d_in[1];
  const float* cb = (const float*)d_in[2];

  float* out = (float*)d_out;
  float* zq = out;
  float* out_idx_f = out + NPTS * DIM;
  float* out_losses = out + NPTS * DIM + NPTS;

  char* ws = (char*)d_ws;
  const size_t REQ = 44040192ULL;  // 42 MB

  if (ws_size >= REQ) {
    float* h2f = (float*)(ws + 0);                    // 128K
    float* c2f = (float*)(ws + 131072);               // 32K
    float* bv = (float*)(ws + 163840);                // 256K used
    int* bi = (int*)(ws + 688128);                    // 256K used
    float* b2o = (float*)(ws + 1212416);              // 256K used
    int* idx = (int*)(ws + 1736704);                  // 128K
    float* partial = (float*)(ws + 1867776);          // 32K
    int* flagcnt = (int*)(ws + 1900544);              // 4 (+pad)
    int* flaglist = (int*)(ws + 1904640);             // 128K
    unsigned short* hh = (unsigned short*)(ws + 2097152);    // 16M
    unsigned short* hl = (unsigned short*)(ws + 18874368);   // 16M
    unsigned short* chh = (unsigned short*)(ws + 35651584);  // 4M
    unsigned short* cll = (unsigned short*)(ws + 39845888);  // 4M

    hipLaunchKernelGGL(split_norms_kernel, dim3(NPTS / 4), dim3(256), 0, stream,
                       h, hh, hl, h2f, flagcnt);
    hipLaunchKernelGGL(split_norms_kernel, dim3(KCODES / 4), dim3(256), 0, stream,
                       cb, chh, cll, c2f, (int*)nullptr);
    hipLaunchKernelGGL(mfma_argmin_kernel, dim3(512), dim3(512), 0, stream,
                       hh, hl, chh, cll, h2f, c2f, bv, bi, b2o);
    hipLaunchKernelGGL(merge_flag_kernel, dim3(NPTS / 256), dim3(256), 0, stream,
                       bv, bi, b2o, idx, out_idx_f, flagcnt, flaglist);
    hipLaunchKernelGGL(refine_kernel, dim3(512), dim3(256), 0, stream,
                       h, cb, h2f, c2f, flagcnt, flaglist, idx, out_idx_f);
    hipLaunchKernelGGL(gather_kernel, dim3(NPTS / 4), dim3(256), 0, stream,
                       h, cb, maskb, idx, zq, partial);
    hipLaunchKernelGGL(finalize_kernel, dim3(1), dim3(256), 0, stream,
                       partial, maskb, out_losses);
  } else {
    float* h2f = (float*)(ws + 0);
    float* c2f = (float*)(ws + (128 << 10));
    float* bestval = (float*)(ws + (160 << 10));
    int* bestidx = (int*)(ws + (416 << 10));
    int* idx = (int*)(ws + (672 << 10));
    float* partial = (float*)(ws + (800 << 10));

    hipLaunchKernelGGL(norms_kernel, dim3(NPTS / 4), dim3(256), 0, stream, h, h2f);
    hipLaunchKernelGGL(norms_kernel, dim3(KCODES / 4), dim3(256), 0, stream, cb, c2f);
    hipLaunchKernelGGL(argmin_fp32_kernel, dim3(512), dim3(512), 0, stream,
                       h, cb, h2f, c2f, bestval, bestidx);
    hipLaunchKernelGGL(merge2_kernel, dim3(NPTS / 256), dim3(256), 0, stream,
                       bestval, bestidx, idx, out_idx_f);
    hipLaunchKernelGGL(gather_kernel, dim3(NPTS / 4), dim3(256), 0, stream,
                       h, cb, maskb, idx, zq, partial);
    hipLaunchKernelGGL(finalize_kernel, dim3(1), dim3(256), 0, stream,
                       partial, maskb, out_losses);
  }
}